// Round 4
// baseline (252.029 us; speedup 1.0000x reference)
//
#include <hip/hip_runtime.h>
#include <hip/hip_bf16.h>
#include <cmath>

// Problem constants (from reference)
#define N_TOK 32768
#define KDIM  1024
#define ODIM  1024

// GEMM tile: 256x128 block, BK=64, 8 waves duty-split:
//   waves 0-3: mean GEMM (x @ Wm^T), waves 4-7: var GEMM (x^2 @ Wv^T)
// Wave-tile 128x64 (8x4 frags of 16x16x32) -> 384 LDS-bytes per MFMA.
// LDS: double-buffered {AsX 32K | BsM 16K | BsV 16K} = 2 x 64K = 128K.
// One barrier per k-tile; STAGE(kt+1) issued before COMPUTE(kt) (T3-min).
#define BM 256
#define BN 128
#define BK 64
#define NKT (KDIM / BK)   // 16 k-tiles
#define THREADS 512
#define BUFSZ 65536

typedef float          f32x4  __attribute__((ext_vector_type(4)));
typedef __bf16         bf16x8 __attribute__((ext_vector_type(8)));
typedef unsigned short us8    __attribute__((ext_vector_type(8)));
typedef unsigned short us2   __attribute__((ext_vector_type(2)));

// round-to-nearest-even f32 -> bf16 (prep kernel only)
static __device__ __forceinline__ unsigned short f2bf(float f) {
  unsigned u = __builtin_bit_cast(unsigned, f);
  u += 0x7FFFu + ((u >> 16) & 1u);
  return (unsigned short)(u >> 16);
}

// compiler-lowered RNE cvt (emits v_cvt_pk_bf16_f32 when paired)
static __device__ __forceinline__ unsigned short bfc(float f) {
  return __builtin_bit_cast(unsigned short, (__bf16)f);
}

static __device__ __forceinline__ f32x4 mfma16(us8 a, us8 b, f32x4 c) {
  return __builtin_amdgcn_mfma_f32_16x16x32_bf16(
      __builtin_bit_cast(bf16x8, a), __builtin_bit_cast(bf16x8, b), c, 0, 0, 0);
}

static __device__ __forceinline__ void gl_lds16(const void* g, void* l) {
  __builtin_amdgcn_global_load_lds(
      (const __attribute__((address_space(1))) void*)g,
      (__attribute__((address_space(3))) void*)l, 16, 0, 0);
}

// elementwise square of 8 bf16 (exact f32 product, RNE repack)
static __device__ __forceinline__ us8 sqr8(us8 a) {
  us8 r;
#pragma unroll
  for (int i = 0; i < 8; ++i) {
    float f = __builtin_bit_cast(float, (unsigned)a[i] << 16);
    r[i] = bfc(f * f);
  }
  return r;
}

// ---------------------------------------------------------------------------
// Prep: weight_logits [O][I][2] (mag,sgn interleaved) -> bf16 W_mean, W_var
// ---------------------------------------------------------------------------
__global__ void wprep_kernel(const float* __restrict__ wl,
                             unsigned short* __restrict__ wm,
                             unsigned short* __restrict__ wv) {
  int i = blockIdx.x * blockDim.x + threadIdx.x;       // 2 elems each
  f32x4 v = *reinterpret_cast<const f32x4*>(wl + (size_t)i * 4);
  float pm0 = 1.f / (1.f + expf(-v.x));
  float ps0 = 1.f / (1.f + expf(-v.y));
  float pm1 = 1.f / (1.f + expf(-v.z));
  float ps1 = 1.f / (1.f + expf(-v.w));
  float m0 = pm0 * (2.f * ps0 - 1.f);
  float m1 = pm1 * (2.f * ps1 - 1.f);
  float q0 = pm0 - m0 * m0;
  float q1 = pm1 - m1 * m1;
  us2 am = {f2bf(m0), f2bf(m1)};
  us2 av = {f2bf(q0), f2bf(q1)};
  *reinterpret_cast<us2*>(wm + (size_t)i * 2) = am;
  *reinterpret_cast<us2*>(wv + (size_t)i * 2) = av;
}

// ---------------------------------------------------------------------------
__global__ __launch_bounds__(THREADS, 2) void ternary_gemm(
    const float* __restrict__ x,
    const unsigned short* __restrict__ wm,
    const unsigned short* __restrict__ wv,
    const float* __restrict__ scale,
    const float* __restrict__ shift,
    const float* __restrict__ noise,
    float* __restrict__ out) {
  __shared__ alignas(16) char smem[2 * BUFSZ];
  // per buffer: AsX [256][64] bf16 at +0 (32K), BsM [128][64] at +32K,
  //             BsV [128][64] at +48K. All XOR-swizzled: byte ^= (row&7)<<4.

  const int tid  = threadIdx.x;
  const int lane = tid & 63;
  const int w    = tid >> 6;        // 0..7; waves w and w+4 share a SIMD
  const bool isVar = (w >= 4);
  const int p    = w & 3;           // pair id -> output region
  const int wr   = p >> 1;          // region rows wr*128
  const int wc   = p & 1;           // region cols wc*64
  const int l15  = lane & 15;
  const int l4   = lane >> 4;

  // XCD-bijective swizzle (1024 blocks % 8 == 0), bn-inner per XCD
  const int bid = blockIdx.x;
  const int swz = (bid & 7) * 128 + (bid >> 3);
  const int bm  = swz >> 3;         // 0..127
  const int bn  = swz & 7;          // 0..7
  const int rowBase = bm * BM;
  const int colBase = bn * BN;

  f32x4 acc[8][4];
#pragma unroll
  for (int i = 0; i < 8; ++i)
#pragma unroll
    for (int j = 0; j < 4; ++j) acc[i][j] = (f32x4)0.f;

  const float* xb = x + (size_t)rowBase * KDIM;

  // ---- staging helpers -----------------------------------------------------
  // B: 2 x 16KB tiles, 1024 16B-chunks each; linear LDS dest, inv-swz src.
  auto stageB = [&](int kt, char* buf) {
    const int k0 = kt * BK;
    char* BsM = buf + 32768;
    char* BsV = buf + 49152;
#pragma unroll
    for (int c = 0; c < 2; ++c) {
      int flat = c * THREADS + tid;        // 0..1023
      int row  = flat >> 3;                // 0..127
      int j    = flat & 7;
      size_t goff = (size_t)(colBase + row) * KDIM + k0 + ((j ^ (row & 7)) << 3);
      gl_lds16(wm + goff, BsM + flat * 16);
      gl_lds16(wv + goff, BsV + flat * 16);
    }
  };
  // x: 256x64 f32 -> regs (8 f32x4 / thread)
  auto loadX = [&](int kt, f32x4* ap) {
    const float* xt = xb + kt * BK;
#pragma unroll
    for (int c = 0; c < 4; ++c) {
      int flat = c * THREADS + tid;        // 0..2047
      int row  = flat >> 3;                // 0..255
      int j    = flat & 7;                 // 16B-bf16 chunk (8 elems)
      const float* s = xt + (size_t)row * KDIM + j * 8;
      ap[2 * c]     = *reinterpret_cast<const f32x4*>(s);
      ap[2 * c + 1] = *reinterpret_cast<const f32x4*>(s + 4);
    }
  };
  // regs -> bf16, swizzled ds_write_b128
  auto writeA = [&](const f32x4* ap, char* buf) {
#pragma unroll
    for (int c = 0; c < 4; ++c) {
      int flat = c * THREADS + tid;
      int row  = flat >> 3;
      int j    = flat & 7;
      f32x4 v0 = ap[2 * c], v1 = ap[2 * c + 1];
      us8 o = {bfc(v0.x), bfc(v0.y), bfc(v0.z), bfc(v0.w),
               bfc(v1.x), bfc(v1.y), bfc(v1.z), bfc(v1.w)};
      int off = row * 128 + ((j * 16) ^ ((row & 7) << 4));
      *reinterpret_cast<us8*>(buf + off) = o;
    }
  };

  // ---- prologue: stage tile 0 into buf0 -----------------------------------
  f32x4 ap[8];
  stageB(0, smem);
  loadX(0, ap);
  writeA(ap, smem);
  __syncthreads();   // drains B DMA (vmcnt) + A writes (lgkm)

  // ---- main loop: one barrier per k-tile ----------------------------------
  for (int kt = 0; kt < NKT; ++kt) {
    const char* cur = smem + (size_t)(kt & 1) * BUFSZ;
    char*       nxt = smem + (size_t)((kt + 1) & 1) * BUFSZ;

    // issue next tile's loads first — they fly during compute
    if (kt + 1 < NKT) { stageB(kt + 1, nxt); loadX(kt + 1, ap); }

    // compute from cur
    const char* Ab = cur;
    const char* Bb = cur + 32768 + (isVar ? 16384 : 0);
#pragma unroll
    for (int ks = 0; ks < 2; ++ks) {
      const int kb = ks * 64 + (l4 << 4);
      us8 bf_[4], af[8];
#pragma unroll
      for (int b = 0; b < 4; ++b) {
        int row = wc * 64 + b * 16 + l15;
        bf_[b] = *reinterpret_cast<const us8*>(Bb + row * 128 + (kb ^ ((row & 7) << 4)));
      }
#pragma unroll
      for (int i = 0; i < 8; ++i) {
        int row = wr * 128 + i * 16 + l15;
        af[i] = *reinterpret_cast<const us8*>(Ab + row * 128 + (kb ^ ((row & 7) << 4)));
        if (isVar) af[i] = sqr8(af[i]);
      }
#pragma unroll
      for (int i = 0; i < 8; ++i)
#pragma unroll
        for (int b = 0; b < 4; ++b)
          acc[i][b] = mfma16(af[i], bf_[b], acc[i][b]);
    }

    // convert + write A(kt+1) into nxt (nobody reads nxt until after barrier)
    if (kt + 1 < NKT) writeA(ap, nxt);

    __syncthreads();   // single drain point: B DMA had a full compute phase
  }

  // ---- epilogue: cross-wave exchange, exactly 128KB, 2-way max ------------
  // mean wave ships region rows 64..127 (i=4..7) to Mx; var ships 0..63 to Vx.
  float* Mx = (float*)smem;             // [4][64][64] f32, col ^ ((lr&4)<<2)
  float* Vx = (float*)(smem + 65536);
  if (!isVar) {
#pragma unroll
    for (int i = 4; i < 8; ++i)
#pragma unroll
      for (int b = 0; b < 4; ++b)
#pragma unroll
        for (int j = 0; j < 4; ++j) {
          int lr = (i - 4) * 16 + l4 * 4 + j;
          int lc = b * 16 + l15;
          Mx[(p * 64 + lr) * 64 + (lc ^ ((lr & 4) << 2))] = acc[i][b][j];
        }
  } else {
#pragma unroll
    for (int i = 0; i < 4; ++i)
#pragma unroll
      for (int b = 0; b < 4; ++b)
#pragma unroll
        for (int j = 0; j < 4; ++j) {
          int lr = i * 16 + l4 * 4 + j;
          int lc = b * 16 + l15;
          Vx[(p * 64 + lr) * 64 + (lc ^ ((lr & 4) << 2))] = acc[i][b][j];
        }
  }
  __syncthreads();

  if (!isVar) {
    // finish region rows 0..63: M in regs, V from Vx
#pragma unroll
    for (int i = 0; i < 4; ++i)
#pragma unroll
      for (int b = 0; b < 4; ++b) {
        int col = colBase + wc * 64 + b * 16 + l15;
        float sc = scale[col], sh = shift[col];
#pragma unroll
        for (int j = 0; j < 4; ++j) {
          int lr = i * 16 + l4 * 4 + j;
          float vv = Vx[(p * 64 + lr) * 64 + ((b * 16 + l15) ^ ((lr & 4) << 2))];
          size_t idx = (size_t)(rowBase + wr * 128 + lr) * ODIM + col;
          out[idx] = fmaf(acc[i][b][j] + sqrtf(fmaxf(vv, 0.f)) * noise[idx], sc, sh);
        }
      }
  } else {
    // finish region rows 64..127: V in regs, M from Mx
#pragma unroll
    for (int i = 4; i < 8; ++i)
#pragma unroll
      for (int b = 0; b < 4; ++b) {
        int col = colBase + wc * 64 + b * 16 + l15;
        float sc = scale[col], sh = shift[col];
#pragma unroll
        for (int j = 0; j < 4; ++j) {
          int lr = (i - 4) * 16 + l4 * 4 + j;
          float mm = Mx[(p * 64 + lr) * 64 + ((b * 16 + l15) ^ ((lr & 4) << 2))];
          size_t idx = (size_t)(rowBase + wr * 128 + 64 + lr) * ODIM + col;
          out[idx] = fmaf(mm + sqrtf(fmaxf(acc[i][b][j], 0.f)) * noise[idx], sc, sh);
        }
      }
  }
}

// ---------------------------------------------------------------------------
extern "C" void kernel_launch(void* const* d_in, const int* in_sizes, int n_in,
                              void* d_out, int out_size, void* d_ws, size_t ws_size,
                              hipStream_t stream) {
  const float* x     = (const float*)d_in[0];   // [32768,1024]
  const float* wl    = (const float*)d_in[1];   // [1024,1024,2]
  const float* scale = (const float*)d_in[2];   // [1024]
  const float* shift = (const float*)d_in[3];   // [1024]
  const float* noise = (const float*)d_in[4];   // [32768,1024]
  float* out = (float*)d_out;

  unsigned short* wm = (unsigned short*)d_ws;            // [1024][1024] bf16
  unsigned short* wv = wm + (size_t)ODIM * KDIM;         // [1024][1024] bf16

  wprep_kernel<<<(ODIM * KDIM / 2) / 256, 256, 0, stream>>>(wl, wm, wv);

  // grid = (32768/256) * (1024/128) = 1024 blocks of 512 threads
  ternary_gemm<<<(N_TOK / BM) * (ODIM / BN), THREADS, 0, stream>>>(
      x, wm, wv, scale, shift, noise, out);
}